// Round 6
// baseline (74.511 us; speedup 1.0000x reference)
//
#include <hip/hip_runtime.h>

#define NW 14
#define NT 1024       // 16 waves
#define BATCH 128

// ---------------- compile-time GF(2) permutation bookkeeping ----------------
constexpr unsigned cnot_pc(unsigned j, int c, int t) {
  int pc = 13 - c, pt = 13 - t;
  return j ^ (((j >> pc) & 1u) << pt);
}
constexpr unsigned gperm(unsigned j) {
  j = cnot_pc(j, 13, 0);
  for (int w = 12; w >= 0; --w) j = cnot_pc(j, w, w + 1);
  return j;
}
constexpr unsigned topbit(unsigned x) {
  unsigned h = 1;
  while (x >>= 1) h <<= 1;
  return h;
}

struct CT {
  unsigned M[NW], S[NW], R[NW];
  static constexpr void inv(const unsigned col[NW], unsigned out[NW]) {
    unsigned rm[NW] = {}, ri[NW] = {};
    for (int r = 0; r < NW; ++r) { rm[r] = 0; ri[r] = 1u << r; }
    for (int b = 0; b < NW; ++b)
      for (int r = 0; r < NW; ++r) rm[r] |= ((col[b] >> r) & 1u) << b;
    for (int c = 0; c < NW; ++c) {
      int piv = c;
      while (!((rm[piv] >> c) & 1u)) ++piv;
      unsigned tm = rm[c]; rm[c] = rm[piv]; rm[piv] = tm;
      unsigned ti = ri[c]; ri[c] = ri[piv]; ri[piv] = ti;
      for (int r = 0; r < NW; ++r)
        if (r != c && ((rm[r] >> c) & 1u)) { rm[r] ^= rm[c]; ri[r] ^= ri[c]; }
    }
    for (int r = 0; r < NW; ++r) out[r] = ri[r];
  }
  constexpr CT() : M{}, S{}, R{} {
    unsigned c1[NW] = {}, c2[NW] = {};
    for (int b = 0; b < NW; ++b) { c1[b] = gperm(1u << b); c2[b] = gperm(c1[b]); }
    unsigned i1[NW] = {}, i2[NW] = {};
    inv(c1, i1); inv(c2, i2);
    for (int w = 0; w < NW; ++w) { M[w] = c1[13 - w]; S[w] = i1[13 - w]; R[w] = i2[13 - w]; }
  }
};
static constexpr CT qct{};
static_assert(qct.M[0] == 0x3000u && qct.M[12] == 0x3u && qct.M[13] == 0x3001u, "mask check");
static_assert(qct.M[4] == 0x300u, "mask check");

// ---------------- complex helpers ----------------
__device__ __forceinline__ float2 cmul(float2 a, float2 b) {
  return make_float2(fmaf(a.x, b.x, -a.y * b.y), fmaf(a.x, b.y, a.y * b.x));
}
__device__ __forceinline__ float2 cmadd(float2 a, float2 b, float2 c) {  // a*b + c
  return make_float2(fmaf(a.x, b.x, fmaf(-a.y, b.y, c.x)),
                     fmaf(a.x, b.y, fmaf(a.y, b.x, c.y)));
}

// fused M = RX(ax) * RZ(az) * RY(ay)
__device__ __forceinline__ void make_mat(float ay, float az, float ax_, float2 m[4]) {
  float c, s, ct, st, cr, sr;
  sincosf(0.5f * ay, &s, &c);
  sincosf(0.5f * az, &st, &ct);
  sincosf(0.5f * ax_, &sr, &cr);
  float2 em = make_float2(ct, -st), ep = make_float2(ct, st);
  float2 r00 = make_float2(c * em.x, c * em.y);
  float2 r01 = make_float2(-s * em.x, -s * em.y);
  float2 r10 = make_float2(s * ep.x, s * ep.y);
  float2 r11 = make_float2(c * ep.x, c * ep.y);
  float2 isr = make_float2(0.f, -sr);
  m[0] = cmadd(isr, r10, make_float2(cr * r00.x, cr * r00.y));
  m[1] = cmadd(isr, r11, make_float2(cr * r01.x, cr * r01.y));
  m[2] = cmadd(isr, r00, make_float2(cr * r10.x, cr * r10.y));
  m[3] = cmadd(isr, r01, make_float2(cr * r11.x, cr * r11.y));
}

// ---------------- lane-xor: DPP for bits 0..3, shfl for bits 4,5 ----------------
template <int CTRL> __device__ __forceinline__ int dppi(int x) {
  return __builtin_amdgcn_update_dpp(0, x, CTRL, 0xF, 0xF, true);
}
template <unsigned LM> __device__ __forceinline__ float lane_xor1(float x) {
  if constexpr (LM == 0u) return x;
  else if constexpr (LM >= 16u) {
    return __shfl_xor(x, (int)LM, 64);
  } else {
    int v = __float_as_int(x);
    if constexpr ((LM & 0xCu) == 0xCu) v = dppi<0x140>(v);       // row_mirror: xor 15
    else if constexpr ((LM & 0xCu) == 0x4u) v = dppi<0x141>(v);  // half_mirror: xor 7
    else if constexpr ((LM & 0xCu) == 0x8u) v = dppi<0x128>(v);  // row_ror:8 : xor 8
    constexpr unsigned REM = ((LM & 0xCu) == 0xCu)   ? (LM ^ 0xFu)
                             : ((LM & 0xCu) == 0x4u) ? (LM ^ 0x7u)
                             : ((LM & 0xCu) == 0x8u) ? (LM ^ 0x8u)
                                                     : LM;
    if constexpr (REM != 0u) {
      constexpr int QC = (int)((0u ^ REM) | ((1u ^ REM) << 2) | ((2u ^ REM) << 4) |
                               ((3u ^ REM) << 6));
      v = dppi<QC>(v);
    }
    return __int_as_float(v);
  }
}
template <unsigned LM> __device__ __forceinline__ float2 lane_xor2(float2 v) {
  if constexpr (LM == 0u) return v;
  return make_float2(lane_xor1<LM>(v.x), lane_xor1<LM>(v.y));
}

// ---------------- generic N-amp register gate ----------------
template <int N, unsigned RM, unsigned LM, unsigned SR>
__device__ __forceinline__ void gateN(float2 (&a)[N], const float2* g, bool st_) {
  float2 e00 = g[0], e01 = g[1], e10 = g[2], e11 = g[3];
  float2 f00 = st_ ? e11 : e00, f01 = st_ ? e10 : e01;
  float2 f10 = st_ ? e01 : e10, f11 = st_ ? e00 : e11;
  if constexpr (RM == 0u) {
#pragma unroll
    for (int r = 0; r < N; ++r) {
      float2 p = lane_xor2<LM>(a[r]);
      if (__builtin_popcount((unsigned)r & SR) & 1)
        a[r] = cmadd(f10, p, cmul(f11, a[r]));
      else
        a[r] = cmadd(f01, p, cmul(f00, a[r]));
    }
  } else {
    constexpr unsigned HB = topbit(RM);
#pragma unroll
    for (int r = 0; r < N; ++r) {
      if (r & (int)HB) continue;
      const int r2 = r ^ (int)RM;
      float2 A = a[r], B = a[r2];
      float2 pA = lane_xor2<LM>(B), pB = lane_xor2<LM>(A);
      a[r] = (__builtin_popcount((unsigned)r & SR) & 1) ? cmadd(f10, pA, cmul(f11, A))
                                                        : cmadd(f01, pA, cmul(f00, A));
      a[r2] = (__builtin_popcount((unsigned)r2 & SR) & 1) ? cmadd(f10, pB, cmul(f11, B))
                                                          : cmadd(f01, pB, cmul(f00, B));
    }
  }
}

// ================= KERNEL A =================
// block = bat*2 + h (h=q13). 8192 amps/block, 8/thread.
// Layout: reg {q0,q1,q2}, lane l0..l5 = q3..q8, wave = q9..q12.
// Gates w=12..7 (M within bits 0..6, all reg/DPP-local).
// Handoff ib (within batch): bit0=q0 bits1..3=q6,q7,q8 bits4..6=q9,q10,q11
//   bits7,8=q1,q2 bits9,10,11=q3,q4,q5 bit12=q12 bit13=q13.
template <int W>
__device__ __forceinline__ void applyA(float2 (&a)[8], const float2* g, unsigned qb) {
  constexpr unsigned M = qct.M[W], S = qct.S[W];
  static_assert((M & ~0x7Fu) == 0u, "A gate out of window");
  gateN<8, (M & 7u), ((M >> 3) & 0xFu), (S & 7u)>(a, g, (__popc(qb & S) & 1) != 0);
}

__global__ __launch_bounds__(NT, 4) void qsimA(const float* __restrict__ x,
                                               const float* __restrict__ params,
                                               float2* __restrict__ gbuf,
                                               float* __restrict__ out) {
  __shared__ float2 v0[NW][2];
  __shared__ float2 g1m[NW][4];
  __shared__ float2 Ahi[128];
  __shared__ float2 BloP[16][9];  // row = (q&127)>>3, col = q&7; padded

  const int blk = blockIdx.x;
  const int bat = blk >> 1;
  const unsigned h = (unsigned)blk & 1u;
  const int t = threadIdx.x;

  if (t < NW) {
    float2 m[4];
    make_mat(params[t * 3 + 0] + x[bat * NW + t], params[t * 3 + 1], params[t * 3 + 2], m);
    v0[t][0] = m[0];
    v0[t][1] = m[2];
    make_mat(params[NW * 3 + t * 3 + 0], params[NW * 3 + t * 3 + 1],
             params[NW * 3 + t * 3 + 2], m);
    g1m[t][0] = m[0]; g1m[t][1] = m[1]; g1m[t][2] = m[2]; g1m[t][3] = m[3];
    if (h == 0) out[bat * NW + t] = 0.f;  // zero for B's atomicAdd (runs after A)
  }
  __syncthreads();
  if (t < 128) {
    float2 pa = make_float2(1.f, 0.f);
#pragma unroll
    for (int w = 0; w < 7; ++w) pa = cmul(pa, v0[w][(t >> (6 - w)) & 1]);
    Ahi[t] = pa;
    float2 pb = make_float2(1.f, 0.f);
#pragma unroll
    for (int w = 7; w < 14; ++w) pb = cmul(pb, v0[w][(t >> (13 - w)) & 1]);
    BloP[t >> 3][t & 7] = pb;
  }
  __syncthreads();

  const unsigned ln = (unsigned)t & 63u, wv = (unsigned)t >> 6;

  // init: amp(q) = Ahi[q>>7] * Blo[q&127]; q = h<<13 | wv<<9 | ln<<3 | r
  float2 a[8];
  {
    float2 ahi = Ahi[(h << 6) | (wv << 2) | (ln >> 4)];
#pragma unroll
    for (int r = 0; r < 8; ++r) a[r] = cmul(ahi, BloP[ln & 15][r]);
  }

  const unsigned qb1 = (h << 13) | (wv << 9) | (ln << 3);
  applyA<12>(a, g1m[12], qb1);  // RM=3
  applyA<11>(a, g1m[11], qb1);  // RM=6
  applyA<10>(a, g1m[10], qb1);  // RM=4, LM=1
  applyA<9>(a, g1m[9], qb1);    // LM=3
  applyA<8>(a, g1m[8], qb1);    // LM=6
  applyA<7>(a, g1m[7], qb1);    // LM=C

  // store: float4 = (q0=0,1) pairs; fully line-utilized 128-B segments
  const unsigned ibs = ((unsigned)bat << 14) | (h << 13) | ((wv >> 3) << 12) |
                       (((ln >> 2) & 1u) << 11) | (((ln >> 1) & 1u) << 10) | ((ln & 1u) << 9) |
                       (((wv >> 2) & 1u) << 6) | (((wv >> 1) & 1u) << 5) | ((wv & 1u) << 4) |
                       (((ln >> 5) & 1u) << 3) | (((ln >> 4) & 1u) << 2) | (((ln >> 3) & 1u) << 1);
  float4* g4 = (float4*)gbuf;
#pragma unroll
  for (int k = 0; k < 4; ++k) {
    const unsigned ib = ibs | ((unsigned)(k & 1) << 7) | ((unsigned)(k >> 1) << 8);
    g4[ib >> 1] = make_float4(a[2 * k].x, a[2 * k].y, a[2 * k + 1].x, a[2 * k + 1].y);
  }
}

// ================= KERNEL B =================
// block = bat*2 + j (j=q5). reg {q0,q12,q13}; lane l0..l5 = q6..q11; wave = q1..q4.
// Gates w=6..1, 0, 13 (M within bits {0,6..13}); then WHT measurement.
template <int W>
__device__ __forceinline__ void applyB(float2 (&a)[8], const float2* g, unsigned qb) {
  constexpr unsigned M = qct.M[W], S = qct.S[W];
  static_assert((M & 0x003Eu) == 0u, "B gate out of window");
  constexpr unsigned RM = (M & 1u) | (((M >> 12) & 1u) << 1) | (((M >> 13) & 1u) << 2);
  constexpr unsigned LM = (M >> 6) & 0x3Fu;
  constexpr unsigned SR = (S & 1u) | (((S >> 12) & 1u) << 1) | (((S >> 13) & 1u) << 2);
  gateN<8, RM, LM, SR>(a, g, (__popc(qb & S) & 1) != 0);
}

__global__ __launch_bounds__(NT, 4) void qsimB(const float* __restrict__ params,
                                               const float2* __restrict__ gbuf,
                                               float* __restrict__ out) {
  __shared__ float2 gB[8][4];   // wires {6,5,4,3,2,1,0,13}
  __shared__ float red[16][NW];

  const int blk = blockIdx.x;
  const int bat = blk >> 1;
  const unsigned j = (unsigned)blk & 1u;  // q5
  const int t = threadIdx.x;

  if (t < 8) {
    constexpr int BW[8] = {6, 5, 4, 3, 2, 1, 0, 13};
    const int w = BW[t];
    float2 m[4];
    make_mat(params[NW * 3 + w * 3 + 0], params[NW * 3 + w * 3 + 1],
             params[NW * 3 + w * 3 + 2], m);
    gB[t][0] = m[0]; gB[t][1] = m[1]; gB[t][2] = m[2]; gB[t][3] = m[3];
  }
  __syncthreads();

  const unsigned l = (unsigned)t & 63u, v = (unsigned)t >> 6;
  const unsigned qb = (l << 6) | (v << 1) | (j << 5);  // reg bits {0,12,13} zero
  const unsigned ibb = ((unsigned)bat << 14) | (l << 1) | (v << 7) | (j << 11);

  // loads: 4 x float4, perfectly linear per wave (1 KB contiguous)
  float2 a[8];  // a[r], r = q13 q12 q0
  const float4* g4 = (const float4*)gbuf;
#pragma unroll
  for (int k2 = 0; k2 < 4; ++k2) {
    const unsigned ib = ibb | ((unsigned)(k2 & 1) << 12) | ((unsigned)(k2 >> 1) << 13);
    const float4 f = g4[ib >> 1];
    a[2 * k2] = make_float2(f.x, f.y);
    a[2 * k2 + 1] = make_float2(f.z, f.w);
  }

  applyB<6>(a, gB[0], qb);    // LM=3
  applyB<5>(a, gB[1], qb);    // LM=6
  applyB<4>(a, gB[2], qb);    // LM=C
  applyB<3>(a, gB[3], qb);    // LM=0x18 (shfl)
  applyB<2>(a, gB[4], qb);    // LM=0x30 (shfl)
  applyB<1>(a, gB[5], qb);    // RM=2, LM=0x20 (shfl)
  applyB<0>(a, gB[6], qb);    // RM=6
  applyB<13>(a, gB[7], qb);   // RM=7

  // measurement: WHT over reg bits {q0,q12,q13}, sign from parity(qb & R)
  float T[8];
#pragma unroll
  for (int r = 0; r < 8; ++r) T[r] = fmaf(a[r].x, a[r].x, a[r].y * a[r].y);
#pragma unroll
  for (int s = 1; s < 8; s <<= 1) {
#pragma unroll
    for (int r = 0; r < 8; ++r) {
      if (!(r & s)) {
        float u = T[r], w_ = T[r ^ s];
        T[r] = u + w_;
        T[r ^ s] = u - w_;
      }
    }
  }

#pragma unroll
  for (int w = 0; w < NW; ++w) {
    constexpr unsigned Rr[NW] = {qct.R[0], qct.R[1], qct.R[2], qct.R[3], qct.R[4],
                                 qct.R[5], qct.R[6], qct.R[7], qct.R[8], qct.R[9],
                                 qct.R[10], qct.R[11], qct.R[12], qct.R[13]};
    const unsigned R = Rr[w];
    const unsigned m = (R & 1u) | (((R >> 12) & 1u) << 1) | (((R >> 13) & 1u) << 2);
    float val = T[m];
    val = (__popc(qb & R) & 1) ? -val : val;
    val += lane_xor1<1>(val);
    val += lane_xor1<2>(val);
    { float u = lane_xor1<4>(val); val += u; }
    val += lane_xor1<8>(val);
    val += __shfl_xor(val, 16, 64);
    val += __shfl_xor(val, 32, 64);
    if ((t & 63) == 0) red[v][w] = val;
  }
  __syncthreads();
  if (t < NW) {
    float s = 0.f;
#pragma unroll
    for (int i = 0; i < 16; ++i) s += red[i][t];
    atomicAdd(&out[bat * NW + t], s);
  }
}

extern "C" void kernel_launch(void* const* d_in, const int* in_sizes, int n_in,
                              void* d_out, int out_size, void* d_ws, size_t ws_size,
                              hipStream_t stream) {
  (void)in_sizes; (void)n_in; (void)ws_size; (void)out_size;
  const float* x = (const float*)d_in[0];
  const float* params = (const float*)d_in[1];
  float* out = (float*)d_out;
  float2* gbuf = (float2*)d_ws;  // 128*16384 float2 = 16 MB

  qsimA<<<dim3(2 * BATCH), dim3(NT), 0, stream>>>(x, params, gbuf, out);
  qsimB<<<dim3(2 * BATCH), dim3(NT), 0, stream>>>(params, gbuf, out);
}

// Round 7
// 69.898 us; speedup vs baseline: 1.0660x; 1.0660x over previous
//
#include <hip/hip_runtime.h>

#define NW 14
#define NT 1024       // 16 waves
#define BATCH 128

typedef float v2f __attribute__((ext_vector_type(2)));  // {re, im} -> pk lo/hi

// ---------------- compile-time GF(2) permutation bookkeeping ----------------
constexpr unsigned cnot_pc(unsigned j, int c, int t) {
  int pc = 13 - c, pt = 13 - t;
  return j ^ (((j >> pc) & 1u) << pt);
}
constexpr unsigned gperm(unsigned j) {
  j = cnot_pc(j, 13, 0);
  for (int w = 12; w >= 0; --w) j = cnot_pc(j, w, w + 1);
  return j;
}
constexpr unsigned topbit(unsigned x) {
  unsigned h = 1;
  while (x >>= 1) h <<= 1;
  return h;
}

struct CT {
  unsigned M[NW], S[NW], R[NW];
  static constexpr void inv(const unsigned col[NW], unsigned out[NW]) {
    unsigned rm[NW] = {}, ri[NW] = {};
    for (int r = 0; r < NW; ++r) { rm[r] = 0; ri[r] = 1u << r; }
    for (int b = 0; b < NW; ++b)
      for (int r = 0; r < NW; ++r) rm[r] |= ((col[b] >> r) & 1u) << b;
    for (int c = 0; c < NW; ++c) {
      int piv = c;
      while (!((rm[piv] >> c) & 1u)) ++piv;
      unsigned tm = rm[c]; rm[c] = rm[piv]; rm[piv] = tm;
      unsigned ti = ri[c]; ri[c] = ri[piv]; ri[piv] = ti;
      for (int r = 0; r < NW; ++r)
        if (r != c && ((rm[r] >> c) & 1u)) { rm[r] ^= rm[c]; ri[r] ^= ri[c]; }
    }
    for (int r = 0; r < NW; ++r) out[r] = ri[r];
  }
  constexpr CT() : M{}, S{}, R{} {
    unsigned c1[NW] = {}, c2[NW] = {};
    for (int b = 0; b < NW; ++b) { c1[b] = gperm(1u << b); c2[b] = gperm(c1[b]); }
    unsigned i1[NW] = {}, i2[NW] = {};
    inv(c1, i1); inv(c2, i2);
    for (int w = 0; w < NW; ++w) { M[w] = c1[13 - w]; S[w] = i1[13 - w]; R[w] = i2[13 - w]; }
  }
};
static constexpr CT qct{};
static_assert(qct.M[0] == 0x3000u && qct.M[12] == 0x3u && qct.M[13] == 0x3001u, "mask check");
static_assert(qct.M[4] == 0x300u, "mask check");

// ---------------- complex helpers (packed) ----------------
__device__ __forceinline__ v2f vswap(v2f m) {  // i*conj-ish: {-im, re}
  v2f r;
  r.x = -m.y;
  r.y = m.x;
  return r;
}
// full complex mul (both varying; used only in prologue/init tables)
__device__ __forceinline__ v2f cmulv(v2f a, v2f b) {
  v2f r;
  r.x = fmaf(a.x, b.x, -a.y * b.y);
  r.y = fmaf(a.x, b.y, a.y * b.x);
  return r;
}

// fused M = RX(ax) * RZ(az) * RY(ay)  (prologue only; 28 threads)
__device__ __forceinline__ void make_mat(float ay, float az, float ax_, v2f m[4]) {
  float c, s, ct, st, cr, sr;
  __sincosf(0.5f * ay, &s, &c);
  __sincosf(0.5f * az, &st, &ct);
  __sincosf(0.5f * ax_, &sr, &cr);
  v2f em, ep;
  em.x = ct; em.y = -st;
  ep.x = ct; ep.y = st;
  v2f r00 = c * em, r01 = -s * em, r10 = s * ep, r11 = c * ep;
  v2f isr;
  isr.x = 0.f; isr.y = -sr;
  m[0] = cmulv(isr, r10) + cr * r00;
  m[1] = cmulv(isr, r11) + cr * r01;
  m[2] = cmulv(isr, r00) + cr * r10;
  m[3] = cmulv(isr, r01) + cr * r11;
}

// ---------------- lane-xor: DPP for bits 0..3, shfl for bits 4,5 ----------------
template <int CTRL> __device__ __forceinline__ int dppi(int x) {
  return __builtin_amdgcn_update_dpp(0, x, CTRL, 0xF, 0xF, true);
}
template <unsigned LM> __device__ __forceinline__ float lane_xor1(float x) {
  if constexpr (LM == 0u) return x;
  else if constexpr (LM >= 16u) {
    return __shfl_xor(x, (int)LM, 64);
  } else {
    int v = __float_as_int(x);
    if constexpr ((LM & 0xCu) == 0xCu) v = dppi<0x140>(v);       // row_mirror: xor 15
    else if constexpr ((LM & 0xCu) == 0x4u) v = dppi<0x141>(v);  // half_mirror: xor 7
    else if constexpr ((LM & 0xCu) == 0x8u) v = dppi<0x128>(v);  // row_ror:8 : xor 8
    constexpr unsigned REM = ((LM & 0xCu) == 0xCu)   ? (LM ^ 0xFu)
                             : ((LM & 0xCu) == 0x4u) ? (LM ^ 0x7u)
                             : ((LM & 0xCu) == 0x8u) ? (LM ^ 0x8u)
                                                     : LM;
    if constexpr (REM != 0u) {
      constexpr int QC = (int)((0u ^ REM) | ((1u ^ REM) << 2) | ((2u ^ REM) << 4) |
                               ((3u ^ REM) << 6));
      v = dppi<QC>(v);
    }
    return __int_as_float(v);
  }
}
template <unsigned LM> __device__ __forceinline__ v2f lane_xor2(v2f v) {
  if constexpr (LM == 0u) return v;
  v2f r;
  r.x = lane_xor1<LM>(v.x);
  r.y = lane_xor1<LM>(v.y);
  return r;
}

// ---------------- generic 16-amp register gate (packed math) ----------------
// out(amp) = self.x*F + self.y*Fs + partner.x*H + partner.y*Hs  (4 pk ops/amp)
// RM: reg-space pair mask; LM: lane xor mask; SR: reg-space S bits.
template <unsigned RM, unsigned LM, unsigned SR>
__device__ __forceinline__ void gate16(v2f (&a)[16], const v2f* gm, const v2f* gs,
                                       bool st_) {
  const v2f e00 = gm[0], e01 = gm[1], e10 = gm[2], e11 = gm[3];
  const v2f s00 = gs[0], s01 = gs[1], s10 = gs[2], s11 = gs[3];
  // pre-swap roles by thread-uniform parity st_
  const v2f f00 = st_ ? e11 : e00, f01 = st_ ? e10 : e01;
  const v2f f10 = st_ ? e01 : e10, f11 = st_ ? e00 : e11;
  const v2f h00 = st_ ? s11 : s00, h01 = st_ ? s10 : s01;
  const v2f h10 = st_ ? s01 : s10, h11 = st_ ? s00 : s11;
  if constexpr (RM == 0u) {
#pragma unroll
    for (int r = 0; r < 16; ++r) {
      const v2f p = lane_xor2<LM>(a[r]);
      const v2f A = a[r];
      if (__builtin_popcount((unsigned)r & SR) & 1)
        a[r] = A.x * f11 + A.y * h11 + p.x * f10 + p.y * h10;
      else
        a[r] = A.x * f00 + A.y * h00 + p.x * f01 + p.y * h01;
    }
  } else {
    constexpr unsigned HB = topbit(RM);
#pragma unroll
    for (int r = 0; r < 16; ++r) {
      if (r & (int)HB) continue;
      const int r2 = r ^ (int)RM;
      const v2f A = a[r], B = a[r2];
      const v2f pA = lane_xor2<LM>(B), pB = lane_xor2<LM>(A);
      a[r] = (__builtin_popcount((unsigned)r & SR) & 1)
                 ? (A.x * f11 + A.y * h11 + pA.x * f10 + pA.y * h10)
                 : (A.x * f00 + A.y * h00 + pA.x * f01 + pA.y * h01);
      a[r2] = (__builtin_popcount((unsigned)r2 & SR) & 1)
                  ? (B.x * f11 + B.y * h11 + pB.x * f10 + pB.y * h10)
                  : (B.x * f00 + B.y * h00 + pB.x * f01 + pB.y * h01);
    }
  }
}

// ================= SINGLE KERNEL (R5 structure, packed math) =================
// One block per batch element; 16384 amps in registers (16 v2f/thread).
// Phase 1 layout: q = wv<<10 | ln<<4 | r   (reg=q0..3, lane=q4..9, wave=q10..13)
// Phase 2 layout: q = r<<10 | qb2          (reg=q10..13, lane0=q0, lane1=q9,
//   lane2..5=q1..4, wave=q5..8)
template <int W>
__device__ __forceinline__ void applyP1(v2f (&a)[16], const v2f* gm, const v2f* gs,
                                        unsigned qb) {
  constexpr unsigned M = qct.M[W], S = qct.S[W];
  static_assert((M & ~0x3FFu) == 0u, "P1 gate out of window");
  gate16<(M & 0xFu), ((M >> 4) & 0x3Fu), (S & 0xFu)>(a, gm, gs, (__popc(qb & S) & 1) != 0);
}
template <int W>
__device__ __forceinline__ void applyP2(v2f (&a)[16], const v2f* gm, const v2f* gs,
                                        unsigned qb) {
  constexpr unsigned M = qct.M[W], S = qct.S[W];
  static_assert((M & ~0x3E01u) == 0u, "P2 gate out of window");
  gate16<((M >> 10) & 0xFu), ((M & 1u) | (((M >> 9) & 1u) << 1)), ((S >> 10) & 0xFu)>(
      a, gm, gs, (__popc(qb & S) & 1) != 0);
}

// launch_bounds(1024,4): 4 waves/EU -> 128-VGPR cap (prevents the R2 spill).
__global__ __launch_bounds__(NT, 4) void qsim(const float* __restrict__ x,
                                              const float* __restrict__ params,
                                              float* __restrict__ out) {
  __shared__ v2f stx[16384];   // 128 KB transpose buffer
  __shared__ v2f v0[NW][2];    // layer-0 fused column
  __shared__ v2f g1m[NW][4];   // layer-1 fused 2x2
  __shared__ v2f g1s[NW][4];   // swapped variants {-im, re}
  __shared__ v2f Ahi[128];
  __shared__ v2f BloP[8][17];  // padded rows
  __shared__ float red[16][NW];

  const int bat = blockIdx.x;
  const int t = threadIdx.x;
  const unsigned ln = (unsigned)t & 63u, wv = (unsigned)t >> 6;

  // prologue spread over 28 threads; __sincosf (HW sin/cos)
  if (t < 2 * NW) {
    const int layer = (t >= NW);
    const int w = t - layer * NW;
    v2f m[4];
    if (!layer) {
      make_mat(params[w * 3 + 0] + x[bat * NW + w], params[w * 3 + 1], params[w * 3 + 2], m);
      v0[w][0] = m[0];
      v0[w][1] = m[2];
    } else {
      make_mat(params[NW * 3 + w * 3 + 0], params[NW * 3 + w * 3 + 1],
               params[NW * 3 + w * 3 + 2], m);
      g1m[w][0] = m[0]; g1m[w][1] = m[1]; g1m[w][2] = m[2]; g1m[w][3] = m[3];
      g1s[w][0] = vswap(m[0]); g1s[w][1] = vswap(m[1]);
      g1s[w][2] = vswap(m[2]); g1s[w][3] = vswap(m[3]);
    }
  }
  __syncthreads();
  if (t < 128) {
    v2f pa; pa.x = 1.f; pa.y = 0.f;
#pragma unroll
    for (int w = 0; w < 7; ++w) pa = cmulv(pa, v0[w][(t >> (6 - w)) & 1]);
    Ahi[t] = pa;
    v2f pb; pb.x = 1.f; pb.y = 0.f;
#pragma unroll
    for (int w = 7; w < 14; ++w) pb = cmulv(pb, v0[w][(t >> (13 - w)) & 1]);
    BloP[t >> 4][t & 15] = pb;
  }
  __syncthreads();

  // ---- init: amp(q) = Ahi[q>>7] * Blo[q&127]; ahi thread-uniform -> hoist swap
  v2f a[16];
  {
    const v2f ahi = Ahi[(wv << 3) | (ln >> 3)];
    const v2f ahis = vswap(ahi);
#pragma unroll
    for (int r = 0; r < 16; ++r) {
      const v2f b = BloP[ln & 7][r];
      a[r] = b.x * ahi + b.y * ahis;
    }
  }

  // ---- phase-1 gates ----
  const unsigned qb1 = (ln << 4) | (wv << 10);
  applyP1<12>(a, g1m[12], g1s[12], qb1);  // RM=3
  applyP1<11>(a, g1m[11], g1s[11], qb1);  // RM=6
  applyP1<10>(a, g1m[10], g1s[10], qb1);  // RM=12
  applyP1<9>(a, g1m[9], g1s[9], qb1);     // RM=8, LM=1 (DPP)
  applyP1<8>(a, g1m[8], g1s[8], qb1);     // LM=3  (DPP)
  applyP1<7>(a, g1m[7], g1s[7], qb1);     // LM=6  (DPP)
  applyP1<6>(a, g1m[6], g1s[6], qb1);     // LM=12 (DPP)
  applyP1<5>(a, g1m[5], g1s[5], qb1);     // LM=24 (shfl)
  applyP1<4>(a, g1m[4], g1s[4], qb1);     // LM=48 (shfl)

  // ---- transpose through XOR-swizzled LDS: slot(q) = q ^ ((q>>4)&0xF) ----
  {
    const unsigned bw = (wv << 10) | (ln << 4) | (ln & 0xFu);
#pragma unroll
    for (int r = 0; r < 16; ++r) stx[bw ^ (unsigned)r] = a[r];
  }
  __syncthreads();
  const unsigned qb2 = (ln & 1u) | (((ln >> 2) & 0xFu) << 1) | (wv << 5) |
                       (((ln >> 1) & 1u) << 9);
  {
    const unsigned c2 = ((ln >> 5) & 1u) | ((wv & 7u) << 1);
    const unsigned br = qb2 ^ c2;
#pragma unroll
    for (int r = 0; r < 16; ++r) a[r] = stx[br | ((unsigned)r << 10)];
  }

  // ---- phase-2 gates ----
  applyP2<3>(a, g1m[3], g1s[3], qb2);     // RM=1, LM=2 (DPP)
  applyP2<2>(a, g1m[2], g1s[2], qb2);     // RM=3
  applyP2<1>(a, g1m[1], g1s[1], qb2);     // RM=6
  applyP2<0>(a, g1m[0], g1s[0], qb2);     // RM=12
  applyP2<13>(a, g1m[13], g1s[13], qb2);  // RM=12, LM=1 (DPP)

  // ---- measurement: WHT over the 4 reg bits (q10..13), sign from parity(qb2&R) ----
  float T[16];
#pragma unroll
  for (int r = 0; r < 16; ++r) T[r] = fmaf(a[r].x, a[r].x, a[r].y * a[r].y);
#pragma unroll
  for (int s = 1; s < 16; s <<= 1) {
#pragma unroll
    for (int r = 0; r < 16; ++r) {
      if (!(r & s)) {
        float u = T[r], v = T[r ^ s];
        T[r] = u + v;
        T[r ^ s] = u - v;
      }
    }
  }

#pragma unroll
  for (int w = 0; w < NW; ++w) {
    constexpr unsigned Rr[NW] = {qct.R[0], qct.R[1], qct.R[2], qct.R[3], qct.R[4],
                                 qct.R[5], qct.R[6], qct.R[7], qct.R[8], qct.R[9],
                                 qct.R[10], qct.R[11], qct.R[12], qct.R[13]};
    const unsigned R = Rr[w];
    float val = T[(R >> 10) & 0xFu];
    val = (__popc(qb2 & R) & 1) ? -val : val;
    val += lane_xor1<1>(val);
    val += lane_xor1<2>(val);
    { float u = lane_xor1<4>(val); val += u; }
    val += lane_xor1<8>(val);
    val += __shfl_xor(val, 16, 64);
    val += __shfl_xor(val, 32, 64);
    if ((t & 63) == 0) red[wv][w] = val;
  }
  __syncthreads();
  if (t < NW) {
    float s = 0.f;
#pragma unroll
    for (int i = 0; i < 16; ++i) s += red[i][t];
    out[bat * NW + t] = s;
  }
}

extern "C" void kernel_launch(void* const* d_in, const int* in_sizes, int n_in,
                              void* d_out, int out_size, void* d_ws, size_t ws_size,
                              hipStream_t stream) {
  (void)in_sizes; (void)n_in; (void)d_ws; (void)ws_size; (void)out_size;
  const float* x = (const float*)d_in[0];
  const float* params = (const float*)d_in[1];
  float* out = (float*)d_out;
  qsim<<<dim3(BATCH), dim3(NT), 0, stream>>>(x, params, out);
}

// Round 9
// 68.288 us; speedup vs baseline: 1.0911x; 1.0236x over previous
//
#include <hip/hip_runtime.h>

#define NW 14
#define NT 1024       // 16 waves
#define BATCH 128

typedef float v2f __attribute__((ext_vector_type(2)));  // {re, im}

// ---------------- compile-time GF(2) permutation bookkeeping ----------------
constexpr unsigned cnot_pc(unsigned j, int c, int t) {
  int pc = 13 - c, pt = 13 - t;
  return j ^ (((j >> pc) & 1u) << pt);
}
constexpr unsigned gperm(unsigned j) {
  j = cnot_pc(j, 13, 0);
  for (int w = 12; w >= 0; --w) j = cnot_pc(j, w, w + 1);
  return j;
}
constexpr int pcnt(unsigned x) {
  int c = 0;
  while (x) { c += (int)(x & 1u); x >>= 1; }
  return c;
}

struct CT {
  unsigned M[NW], S[NW], R[NW];
  static constexpr void inv(const unsigned col[NW], unsigned out[NW]) {
    unsigned rm[NW] = {}, ri[NW] = {};
    for (int r = 0; r < NW; ++r) { rm[r] = 0; ri[r] = 1u << r; }
    for (int b = 0; b < NW; ++b)
      for (int r = 0; r < NW; ++r) rm[r] |= ((col[b] >> r) & 1u) << b;
    for (int c = 0; c < NW; ++c) {
      int piv = c;
      while (!((rm[piv] >> c) & 1u)) ++piv;
      unsigned tm = rm[c]; rm[c] = rm[piv]; rm[piv] = tm;
      unsigned ti = ri[c]; ri[c] = ri[piv]; ri[piv] = ti;
      for (int r = 0; r < NW; ++r)
        if (r != c && ((rm[r] >> c) & 1u)) { rm[r] ^= rm[c]; ri[r] ^= ri[c]; }
    }
    for (int r = 0; r < NW; ++r) out[r] = ri[r];
  }
  constexpr CT() : M{}, S{}, R{} {
    unsigned c1[NW] = {}, c2[NW] = {};
    for (int b = 0; b < NW; ++b) { c1[b] = gperm(1u << b); c2[b] = gperm(c1[b]); }
    unsigned i1[NW] = {}, i2[NW] = {};
    inv(c1, i1); inv(c2, i2);
    for (int w = 0; w < NW; ++w) { M[w] = c1[13 - w]; S[w] = i1[13 - w]; R[w] = i2[13 - w]; }
  }
};
static constexpr CT qct{};
static_assert(qct.M[0] == 0x3000u && qct.M[12] == 0x3u && qct.M[13] == 0x3001u, "mask check");

// ---- b-space: storage b holds physical q = P1(b); closed form + compile-time proofs ----
constexpr unsigned p1f(unsigned b) {
  return ((b ^ (b >> 1)) ^ ((b & 1u) * 0x3000u)) & 0x3FFFu;
}
constexpr bool chk_p1_formula() {
  for (unsigned b = 0; b < 16384u; ++b)
    if (p1f(b) != gperm(b)) return false;
  return true;
}
static_assert(chk_p1_formula(), "P1 closed form == gperm");
// role: logical bit w of amp stored at b is bit (13-w) of b  (vs verified S-parity)
constexpr bool chk_role() {
  for (int w = 0; w < NW; ++w) {
    for (unsigned b = 0; b < 16384u; b += 37u)
      if ((unsigned)(pcnt(p1f(b) & qct.S[w]) & 1) != ((b >> (13 - w)) & 1u)) return false;
    for (int j = 0; j < 14; ++j)
      if ((unsigned)(pcnt(p1f(1u << j) & qct.S[w]) & 1) != (((1u << j) >> (13 - w)) & 1u))
        return false;
  }
  return true;
}
static_assert(chk_role(), "b-space role = storage bit");
// measurement masks in b-space: parity(b & RB[w]) == parity(P1(b) & R[w])
struct RBt {
  unsigned v[NW];
  constexpr RBt() : v{} {
    for (int w = 0; w < NW; ++w) {
      unsigned m = 0;
      for (int j = 0; j < 14; ++j)
        if (pcnt(gperm(1u << j) & qct.R[w]) & 1) m |= 1u << j;
      v[w] = m;
    }
  }
};
static constexpr RBt rbt{};
constexpr bool chk_meas() {
  for (int w = 0; w < NW; ++w)
    for (unsigned b = 0; b < 16384u; b += 41u)
      if ((pcnt(p1f(b) & qct.R[w]) & 1) != (pcnt(b & rbt.v[w]) & 1)) return false;
  return true;
}
static_assert(chk_meas(), "b-space measurement masks");
// init offset: P1 is GF(2)-linear, so P1(r<<1) = (r<<1)^r (XOR, not 3r!). It stays
// below bit 7, so the Ahi index (q>>7) is thread-uniform across the 16 amps.
constexpr bool chk_cr() {
  for (unsigned r = 0; r < 16u; ++r)
    if (p1f(r << 1) != ((r << 1) ^ r) || p1f(r << 1) >= 128u) return false;
  return true;
}
static_assert(chk_cr(), "P1(r<<1) == (r<<1)^r and < 128");

// ---------------- complex helpers (packed) ----------------
__device__ __forceinline__ v2f vswap(v2f m) {  // {-im, re}
  v2f r;
  r.x = -m.y;
  r.y = m.x;
  return r;
}
__device__ __forceinline__ v2f cmulv(v2f a, v2f b) {
  v2f r;
  r.x = fmaf(a.x, b.x, -a.y * b.y);
  r.y = fmaf(a.x, b.y, a.y * b.x);
  return r;
}

// fused M = RX(ax) * RZ(az) * RY(ay)  (prologue only)
__device__ __forceinline__ void make_mat(float ay, float az, float ax_, v2f m[4]) {
  float c, s, ct, st, cr, sr;
  __sincosf(0.5f * ay, &s, &c);
  __sincosf(0.5f * az, &st, &ct);
  __sincosf(0.5f * ax_, &sr, &cr);
  v2f em, ep;
  em.x = ct; em.y = -st;
  ep.x = ct; ep.y = st;
  v2f r00 = c * em, r01 = -s * em, r10 = s * ep, r11 = c * ep;
  v2f isr;
  isr.x = 0.f; isr.y = -sr;
  m[0] = cmulv(isr, r10) + cr * r00;
  m[1] = cmulv(isr, r11) + cr * r01;
  m[2] = cmulv(isr, r00) + cr * r10;
  m[3] = cmulv(isr, r01) + cr * r11;
}

// ---------------- DPP lane-xor (lane bits 0..3 only) ----------------
template <int CTRL> __device__ __forceinline__ int dppi(int x) {
  return __builtin_amdgcn_update_dpp(0, x, CTRL, 0xF, 0xF, true);
}
template <unsigned LM> __device__ __forceinline__ float lane_xor1(float x) {
  if constexpr (LM == 0u) return x;
  else if constexpr (LM >= 16u) {
    return __shfl_xor(x, (int)LM, 64);
  } else {
    int v = __float_as_int(x);
    if constexpr ((LM & 0xCu) == 0xCu) v = dppi<0x140>(v);       // row_mirror
    else if constexpr ((LM & 0xCu) == 0x4u) v = dppi<0x141>(v);  // half_mirror
    else if constexpr ((LM & 0xCu) == 0x8u) v = dppi<0x128>(v);  // row_ror:8
    constexpr unsigned REM = ((LM & 0xCu) == 0xCu)   ? (LM ^ 0xFu)
                             : ((LM & 0xCu) == 0x4u) ? (LM ^ 0x7u)
                             : ((LM & 0xCu) == 0x8u) ? (LM ^ 0x8u)
                                                     : LM;
    if constexpr (REM != 0u) {
      constexpr int QC = (int)((0u ^ REM) | ((1u ^ REM) << 2) | ((2u ^ REM) << 4) |
                               ((3u ^ REM) << 6));
      v = dppi<QC>(v);
    }
    return __int_as_float(v);
  }
}
template <unsigned LM> __device__ __forceinline__ v2f lane_xor2(v2f v) {
  if constexpr (LM == 0u) return v;
  v2f r;
  r.x = lane_xor1<LM>(v.x);
  r.y = lane_xor1<LM>(v.y);
  return r;
}

// ---------------- gates in b-space ----------------
// Matrix block in LDS: G[0]=(m00,m01) G[1]=(m10,m11) G[2]=(s00,s01) G[3]=(s10,s11),
// sXY = vswap(mXY). Complex m*A = A.x*m + A.y*vswap(m).

// reg-local gate: pairs r <-> r|RM; r with bit clear is logical 0. No selects.
template <unsigned RM>
__device__ __forceinline__ void gate_reg(v2f (&a)[16], const float4* G) {
  const float4 A0 = G[0], A1 = G[1], A2 = G[2], A3 = G[3];
  v2f m00, m01, m10, m11, s00, s01, s10, s11;
  m00.x = A0.x; m00.y = A0.y; m01.x = A0.z; m01.y = A0.w;
  m10.x = A1.x; m10.y = A1.y; m11.x = A1.z; m11.y = A1.w;
  s00.x = A2.x; s00.y = A2.y; s01.x = A2.z; s01.y = A2.w;
  s10.x = A3.x; s10.y = A3.y; s11.x = A3.z; s11.y = A3.w;
#pragma unroll
  for (int r = 0; r < 16; ++r) {
    if (r & (int)RM) continue;
    const int r1 = r | (int)RM;
    const v2f A = a[r], B = a[r1];
    a[r] = A.x * m00 + A.y * s00 + B.x * m01 + B.y * s01;
    a[r1] = A.x * m10 + A.y * s10 + B.x * m11 + B.y * s11;
  }
}

// lane-local gate: partner via DPP xor LM; role = this thread's lane bit (bool).
template <unsigned LM>
__device__ __forceinline__ void gate_dpp(v2f (&a)[16], const float4* G, bool role) {
  const float4 A0 = G[0], A1 = G[1], A2 = G[2], A3 = G[3];
  v2f m00, m01, m10, m11, s00, s01, s10, s11;
  m00.x = A0.x; m00.y = A0.y; m01.x = A0.z; m01.y = A0.w;
  m10.x = A1.x; m10.y = A1.y; m11.x = A1.z; m11.y = A1.w;
  s00.x = A2.x; s00.y = A2.y; s01.x = A2.z; s01.y = A2.w;
  s10.x = A3.x; s10.y = A3.y; s11.x = A3.z; s11.y = A3.w;
  const v2f f0 = role ? m11 : m00, f0s = role ? s11 : s00;
  const v2f f1 = role ? m10 : m01, f1s = role ? s10 : s01;
#pragma unroll
  for (int r = 0; r < 16; ++r) {
    const v2f P = lane_xor2<LM>(a[r]);
    const v2f A = a[r];
    a[r] = A.x * f0 + A.y * f0s + P.x * f1 + P.y * f1s;
  }
}

// ================= SINGLE KERNEL, b-space =================
// Phase 1: reg = b1..b4, lane l0..l5 = b5..b10, wave = (b11,b12,b13,b0).
//   Gates w=12..9 -> RM=1,2,4,8; w=8..5 -> LM=1,2,4,8 (DPP).
// Phase 2 (after LDS transpose): reg r' = (b11,b12,b13,b0),
//   lane l0..l5 = (b9,b10,b5,b6,b7,b8), wave = b1..b4.
//   Gates w=4,3 -> LM=1,2 (DPP); w=2,1,0,13 -> RM=1,2,4,8.  No shfl anywhere.
__global__ __launch_bounds__(NT, 4) void qsim(const float* __restrict__ x,
                                              const float* __restrict__ params,
                                              float* __restrict__ out) {
  __shared__ v2f stx[16384];     // 128 KB transpose buffer
  __shared__ v2f v0[NW][2];
  __shared__ float4 gq[NW][4];   // layer-1 fused gates, packed
  __shared__ v2f Ahi[128];
  __shared__ v2f BloP[8][17];
  __shared__ float red[16][NW];

  const int bat = blockIdx.x;
  const int t = threadIdx.x;
  const unsigned ln = (unsigned)t & 63u, wv = (unsigned)t >> 6;

  if (t < 2 * NW) {
    const int layer = (t >= NW);
    const int w = t - layer * NW;
    v2f m[4];
    if (!layer) {
      make_mat(params[w * 3 + 0] + x[bat * NW + w], params[w * 3 + 1], params[w * 3 + 2], m);
      v0[w][0] = m[0];
      v0[w][1] = m[2];
    } else {
      make_mat(params[NW * 3 + w * 3 + 0], params[NW * 3 + w * 3 + 1],
               params[NW * 3 + w * 3 + 2], m);
      const v2f s0 = vswap(m[0]), s1 = vswap(m[1]), s2 = vswap(m[2]), s3 = vswap(m[3]);
      gq[w][0] = make_float4(m[0].x, m[0].y, m[1].x, m[1].y);
      gq[w][1] = make_float4(m[2].x, m[2].y, m[3].x, m[3].y);
      gq[w][2] = make_float4(s0.x, s0.y, s1.x, s1.y);
      gq[w][3] = make_float4(s2.x, s2.y, s3.x, s3.y);
    }
  }
  __syncthreads();
  if (t < 128) {
    v2f pa; pa.x = 1.f; pa.y = 0.f;
#pragma unroll
    for (int w = 0; w < 7; ++w) pa = cmulv(pa, v0[w][(t >> (6 - w)) & 1]);
    Ahi[t] = pa;
    v2f pb; pb.x = 1.f; pb.y = 0.f;
#pragma unroll
    for (int w = 7; w < 14; ++w) pb = cmulv(pb, v0[w][(t >> (13 - w)) & 1]);
    BloP[t >> 4][t & 15] = pb;
  }
  __syncthreads();

  // ---- phase-1 thread base (reg bits b1..4 = 0) ----
  const unsigned bb = (ln << 5) | ((wv & 7u) << 11) | (wv >> 3);
  const unsigned qb = ((bb ^ (bb >> 1)) ^ ((bb & 1u) * 0x3000u)) & 0x3FFFu;  // P1(bb)

  // ---- init: store[b] = psi0[P1(b)]; P1 linear => q = qb ^ ((r<<1)^r) ----
  v2f a[16];
  {
    const v2f ahi = Ahi[qb >> 7];
    const v2f ahis = vswap(ahi);
    const unsigned q7 = qb & 127u;
#pragma unroll
    for (int r = 0; r < 16; ++r) {
      const unsigned j = q7 ^ (((unsigned)r << 1) ^ (unsigned)r);
      const v2f b = BloP[j >> 4][j & 15u];
      a[r] = b.x * ahi + b.y * ahis;
    }
  }

  // ---- phase-1 gates ----
  gate_reg<1>(a, gq[12]);
  gate_reg<2>(a, gq[11]);
  gate_reg<4>(a, gq[10]);
  gate_reg<8>(a, gq[9]);
  gate_dpp<1>(a, gq[8], (ln & 1u) != 0);         // b5 = l0
  gate_dpp<2>(a, gq[7], (ln & 2u) != 0);         // b6 = l1
  gate_dpp<4>(a, gq[6], (ln & 4u) != 0);         // b7 = l2
  gate_dpp<8>(a, gq[5], (ln & 8u) != 0);         // b8 = l3

  // ---- transpose: slot(b) = b ^ (((b>>5)&0xF)<<1) ----
  {
    const unsigned bw = bb ^ ((ln & 0xFu) << 1);
#pragma unroll
    for (int r = 0; r < 16; ++r) stx[bw ^ ((unsigned)r << 1)] = a[r];
  }
  __syncthreads();
  // phase-2 thread base (bits b1..b10), r' = (b11,b12,b13,b0)
  const unsigned brb = (wv << 1) | (((ln >> 2) & 0xFu) << 5) | ((ln & 1u) << 9) |
                       (((ln >> 1) & 1u) << 10);
  {
    const unsigned br = brb ^ (((brb >> 5) & 0xFu) << 1);
#pragma unroll
    for (int r = 0; r < 16; ++r)
      a[r] = stx[br | (((unsigned)r & 7u) << 11) | ((unsigned)r >> 3)];
  }

  // ---- phase-2 gates ----
  gate_dpp<1>(a, gq[4], (ln & 1u) != 0);         // b9  = l0
  gate_dpp<2>(a, gq[3], (ln & 2u) != 0);         // b10 = l1
  gate_reg<1>(a, gq[2]);
  gate_reg<2>(a, gq[1]);
  gate_reg<4>(a, gq[0]);
  gate_reg<8>(a, gq[13]);

  // ---- measurement: WHT over r' bits, sign from parity(brb & RB) ----
  float T[16];
#pragma unroll
  for (int r = 0; r < 16; ++r) T[r] = fmaf(a[r].x, a[r].x, a[r].y * a[r].y);
#pragma unroll
  for (int s = 1; s < 16; s <<= 1) {
#pragma unroll
    for (int r = 0; r < 16; ++r) {
      if (!(r & s)) {
        float u = T[r], v = T[r ^ s];
        T[r] = u + v;
        T[r ^ s] = u - v;
      }
    }
  }

#pragma unroll
  for (int w = 0; w < NW; ++w) {
    constexpr unsigned Rr[NW] = {rbt.v[0], rbt.v[1], rbt.v[2], rbt.v[3], rbt.v[4],
                                 rbt.v[5], rbt.v[6], rbt.v[7], rbt.v[8], rbt.v[9],
                                 rbt.v[10], rbt.v[11], rbt.v[12], rbt.v[13]};
    const unsigned R = Rr[w];
    const unsigned m = ((R >> 11) & 1u) | (((R >> 12) & 1u) << 1) | (((R >> 13) & 1u) << 2) |
                       ((R & 1u) << 3);
    float val = T[m];
    val = (__popc(brb & R) & 1) ? -val : val;
    val += lane_xor1<1>(val);
    val += lane_xor1<2>(val);
    { float u = lane_xor1<4>(val); val += u; }
    val += lane_xor1<8>(val);
    val += __shfl_xor(val, 16, 64);
    val += __shfl_xor(val, 32, 64);
    if ((t & 63) == 0) red[wv][w] = val;
  }
  __syncthreads();
  if (t < NW) {
    float s = 0.f;
#pragma unroll
    for (int i = 0; i < 16; ++i) s += red[i][t];
    out[bat * NW + t] = s;
  }
}

extern "C" void kernel_launch(void* const* d_in, const int* in_sizes, int n_in,
                              void* d_out, int out_size, void* d_ws, size_t ws_size,
                              hipStream_t stream) {
  (void)in_sizes; (void)n_in; (void)d_ws; (void)ws_size; (void)out_size;
  const float* x = (const float*)d_in[0];
  const float* params = (const float*)d_in[1];
  float* out = (float*)d_out;
  qsim<<<dim3(BATCH), dim3(NT), 0, stream>>>(x, params, out);
}

// Round 11
// 57.864 us; speedup vs baseline: 1.2877x; 1.1801x over previous
//
#include <hip/hip_runtime.h>

#define NW 14
#define NT 1024
#define BATCH 128

typedef float v2f __attribute__((ext_vector_type(2)));  // {re, im}

// ---------------- compile-time GF(2) permutation bookkeeping ----------------
constexpr unsigned cnot_pc(unsigned j, int c, int t) {
  int pc = 13 - c, pt = 13 - t;
  return j ^ (((j >> pc) & 1u) << pt);
}
constexpr unsigned gperm(unsigned j) {
  j = cnot_pc(j, 13, 0);
  for (int w = 12; w >= 0; --w) j = cnot_pc(j, w, w + 1);
  return j;
}
constexpr int pcnt(unsigned x) {
  int c = 0;
  while (x) { c += (int)(x & 1u); x >>= 1; }
  return c;
}

struct CT {
  unsigned M[NW], S[NW], R[NW];
  static constexpr void inv(const unsigned col[NW], unsigned out[NW]) {
    unsigned rm[NW] = {}, ri[NW] = {};
    for (int r = 0; r < NW; ++r) { rm[r] = 0; ri[r] = 1u << r; }
    for (int b = 0; b < NW; ++b)
      for (int r = 0; r < NW; ++r) rm[r] |= ((col[b] >> r) & 1u) << b;
    for (int c = 0; c < NW; ++c) {
      int piv = c;
      while (!((rm[piv] >> c) & 1u)) ++piv;
      unsigned tm = rm[c]; rm[c] = rm[piv]; rm[piv] = tm;
      unsigned ti = ri[c]; ri[c] = ri[piv]; ri[piv] = ti;
      for (int r = 0; r < NW; ++r)
        if (r != c && ((rm[r] >> c) & 1u)) { rm[r] ^= rm[c]; ri[r] ^= ri[c]; }
    }
    for (int r = 0; r < NW; ++r) out[r] = ri[r];
  }
  constexpr CT() : M{}, S{}, R{} {
    unsigned c1[NW] = {}, c2[NW] = {};
    for (int b = 0; b < NW; ++b) { c1[b] = gperm(1u << b); c2[b] = gperm(c1[b]); }
    unsigned i1[NW] = {}, i2[NW] = {};
    inv(c1, i1); inv(c2, i2);
    for (int w = 0; w < NW; ++w) { M[w] = c1[13 - w]; S[w] = i1[13 - w]; R[w] = i2[13 - w]; }
  }
};
static constexpr CT qct{};
static_assert(qct.M[0] == 0x3000u && qct.M[12] == 0x3u && qct.M[13] == 0x3001u, "mask check");

// ---- b-space machinery (hardware-verified in R9; kept for the fallback kernel) ----
constexpr unsigned p1f(unsigned b) {
  return ((b ^ (b >> 1)) ^ ((b & 1u) * 0x3000u)) & 0x3FFFu;
}
constexpr bool chk_p1_formula() {
  for (unsigned b = 0; b < 16384u; ++b)
    if (p1f(b) != gperm(b)) return false;
  return true;
}
static_assert(chk_p1_formula(), "P1 closed form == gperm");
constexpr bool chk_role() {
  for (int w = 0; w < NW; ++w) {
    for (unsigned b = 0; b < 16384u; b += 37u)
      if ((unsigned)(pcnt(p1f(b) & qct.S[w]) & 1) != ((b >> (13 - w)) & 1u)) return false;
    for (int j = 0; j < 14; ++j)
      if ((unsigned)(pcnt(p1f(1u << j) & qct.S[w]) & 1) != (((1u << j) >> (13 - w)) & 1u))
        return false;
  }
  return true;
}
static_assert(chk_role(), "b-space role = storage bit");
struct RBt {
  unsigned v[NW];
  constexpr RBt() : v{} {
    for (int w = 0; w < NW; ++w) {
      unsigned m = 0;
      for (int j = 0; j < 14; ++j)
        if (pcnt(gperm(1u << j) & qct.R[w]) & 1) m |= 1u << j;
      v[w] = m;
    }
  }
};
static constexpr RBt rbt{};
constexpr bool chk_meas() {
  for (int w = 0; w < NW; ++w)
    for (unsigned b = 0; b < 16384u; b += 41u)
      if ((pcnt(p1f(b) & qct.R[w]) & 1) != (pcnt(b & rbt.v[w]) & 1)) return false;
  return true;
}
static_assert(chk_meas(), "b-space measurement masks");
constexpr bool chk_cr() {
  for (unsigned r = 0; r < 16u; ++r)
    if (p1f(r << 1) != ((r << 1) ^ r) || p1f(r << 1) >= 128u) return false;
  return true;
}
static_assert(chk_cr(), "P1(r<<1) == (r<<1)^r and < 128");

// ---------------- generic complex (shared host-constexpr / device) ----------------
template <class T> struct cx { T re, im; };
template <class T> __host__ __device__ constexpr cx<T> operator+(cx<T> a, cx<T> b) {
  return {a.re + b.re, a.im + b.im};
}
template <class T> __host__ __device__ constexpr cx<T> operator-(cx<T> a, cx<T> b) {
  return {a.re - b.re, a.im - b.im};
}
template <class T> __host__ __device__ constexpr cx<T> operator*(cx<T> a, cx<T> b) {
  return {a.re * b.re - a.im * b.im, a.re * b.im + a.im * b.re};
}
template <class T> __host__ __device__ constexpr cx<T> cj(cx<T> a) { return {a.re, -a.im}; }

// ---------------- transfer-matrix contraction (ONE implementation, verified) -------
// E = <s| C^dag (tensor_j M_j) C |s>, C = CNOT(0,1)..CNOT(N-2,N-1), CNOT(N-1,0).
// Ladder on product state: amp(n) = prod_j s_j(n_j ^ n_{j-1}); wrap handled by the
// 4 boundary cases (cb,cp) = (n_{N-1}, n'_{N-1}) with M_0 argument xor-shifted.
// NOTE: all locals zero-initialized — uninitialized reads poison constexpr eval (R10).
template <int N, class T, class FS, class FM>
__host__ __device__ constexpr cx<T> contract_case(const FS& s, const FM& M, int cb, int cp) {
  cx<T> v[2][2] = {};
  for (int q = 0; q < 2; ++q)
    for (int qp = 0; qp < 2; ++qp)
      v[q][qp] = s(0, q) * cj(s(0, qp)) * M(0, qp ^ cp, q ^ cb);
#pragma unroll
  for (int j = 1; j <= N - 2; ++j) {
    cx<T> A[2][2] = {}, B[2][2] = {};
    for (int p = 0; p < 2; ++p) {
      A[p][0] = cj(s(j, 0)) * v[p][0] + cj(s(j, 1)) * v[p][1];
      A[p][1] = cj(s(j, 1)) * v[p][0] + cj(s(j, 0)) * v[p][1];
    }
    for (int qp = 0; qp < 2; ++qp) {
      B[0][qp] = s(j, 0) * A[0][qp] + s(j, 1) * A[1][qp];
      B[1][qp] = s(j, 1) * A[0][qp] + s(j, 0) * A[1][qp];
    }
    for (int q = 0; q < 2; ++q)
      for (int qp = 0; qp < 2; ++qp)
        v[q][qp] = M(j, qp, q) * B[q][qp];
  }
  cx<T> e{0, 0};
  for (int p = 0; p < 2; ++p)
    for (int pp = 0; pp < 2; ++pp)
      e = e + s(N - 1, cb ^ p) * cj(s(N - 1, cp ^ pp)) * v[p][pp];
  return M(N - 1, cp, cb) * e;
}

// ---- compile-time end-to-end check vs brute-force 2^N simulator, random inputs ----
template <int N> constexpr bool chain_check() {
  cx<double> S[N][2] = {};
  cx<double> MM[N][2][2] = {};
  unsigned st8 = 12345u + (unsigned)N * 977u;
  auto nxt = [&st8]() {
    st8 = st8 * 1664525u + 1013904223u;
    return ((double)(st8 >> 8) / 8388608.0) - 1.0;
  };
  for (int j = 0; j < N; ++j) {
    S[j][0] = {nxt(), nxt()};
    S[j][1] = {nxt(), nxt()};
    for (int r = 0; r < 2; ++r)
      for (int c = 0; c < 2; ++c) MM[j][r][c] = {nxt(), nxt()};
  }
  const int SZ = 1 << N;
  cx<double> phi[1 << N] = {}, tmp[1 << N] = {};
  for (int q = 0; q < SZ; ++q) {
    cx<double> a{1, 0};
    for (int j = 0; j < N; ++j) a = a * S[j][(q >> (N - 1 - j)) & 1];
    phi[q] = a;
  }
  // CNOT circuit order (verified cnot_pc semantics: after[q] = before[perm(q)])
  for (int g = 0; g < N; ++g) {
    const int c = (g < N - 1) ? g : (N - 1);
    const int t = (g < N - 1) ? (g + 1) : 0;
    for (int q = 0; q < SZ; ++q)
      tmp[q] = phi[q ^ ((((q >> (N - 1 - c)) & 1)) << (N - 1 - t))];
    for (int q = 0; q < SZ; ++q) phi[q] = tmp[q];
  }
  cx<double> mp[1 << N] = {};
  for (int q = 0; q < SZ; ++q) mp[q] = phi[q];
  for (int j = 0; j < N; ++j) {
    const int bit = 1 << (N - 1 - j);
    for (int q = 0; q < SZ; ++q) {
      if (q & bit) continue;
      cx<double> a0 = mp[q], a1 = mp[q | bit];
      mp[q] = MM[j][0][0] * a0 + MM[j][0][1] * a1;
      mp[q | bit] = MM[j][1][0] * a0 + MM[j][1][1] * a1;
    }
  }
  cx<double> E{0, 0};
  for (int q = 0; q < SZ; ++q) E = E + cj(phi[q]) * mp[q];
  auto sg = [&S](int j, int b) { return S[j][b]; };
  auto mg = [&MM](int j, int r, int c) { return MM[j][r][c]; };
  cx<double> Tt{0, 0};
  for (int cb = 0; cb < 2; ++cb)
    for (int cp = 0; cp < 2; ++cp)
      Tt = Tt + contract_case<N, double>(sg, mg, cb, cp);
  double dr = Tt.re - E.re, di = Tt.im - E.im;
  if (dr < 0) dr = -dr;
  if (di < 0) di = -di;
  double mag = (E.re < 0 ? -E.re : E.re) + (E.im < 0 ? -E.im : E.im) + 1.0;
  return (dr + di) < 1e-9 * mag;
}
constexpr bool CHAIN_OK = chain_check<4>() && chain_check<5>() && chain_check<6>();

// ---------------- shared device helpers ----------------
__device__ __forceinline__ v2f vswap(v2f m) {
  v2f r;
  r.x = -m.y;
  r.y = m.x;
  return r;
}
__device__ __forceinline__ v2f cmulv(v2f a, v2f b) {
  v2f r;
  r.x = fmaf(a.x, b.x, -a.y * b.y);
  r.y = fmaf(a.x, b.y, a.y * b.x);
  return r;
}
__device__ __forceinline__ void make_mat(float ay, float az, float ax_, v2f m[4]) {
  float c, s, ct, st, cr, sr;
  __sincosf(0.5f * ay, &s, &c);
  __sincosf(0.5f * az, &st, &ct);
  __sincosf(0.5f * ax_, &sr, &cr);
  v2f em, ep;
  em.x = ct; em.y = -st;
  ep.x = ct; ep.y = st;
  v2f r00 = c * em, r01 = -s * em, r10 = s * ep, r11 = c * ep;
  v2f isr;
  isr.x = 0.f; isr.y = -sr;
  m[0] = cmulv(isr, r10) + cr * r00;
  m[1] = cmulv(isr, r11) + cr * r01;
  m[2] = cmulv(isr, r00) + cr * r10;
  m[3] = cmulv(isr, r01) + cr * r11;
}
template <int CTRL> __device__ __forceinline__ int dppi(int x) {
  return __builtin_amdgcn_update_dpp(0, x, CTRL, 0xF, 0xF, true);
}
template <unsigned LM> __device__ __forceinline__ float lane_xor1(float x) {
  if constexpr (LM == 0u) return x;
  else if constexpr (LM >= 16u) {
    return __shfl_xor(x, (int)LM, 64);
  } else {
    int v = __float_as_int(x);
    if constexpr ((LM & 0xCu) == 0xCu) v = dppi<0x140>(v);
    else if constexpr ((LM & 0xCu) == 0x4u) v = dppi<0x141>(v);
    else if constexpr ((LM & 0xCu) == 0x8u) v = dppi<0x128>(v);
    constexpr unsigned REM = ((LM & 0xCu) == 0xCu)   ? (LM ^ 0xFu)
                             : ((LM & 0xCu) == 0x4u) ? (LM ^ 0x7u)
                             : ((LM & 0xCu) == 0x8u) ? (LM ^ 0x8u)
                                                     : LM;
    if constexpr (REM != 0u) {
      constexpr int QC = (int)((0u ^ REM) | ((1u ^ REM) << 2) | ((2u ^ REM) << 4) |
                               ((3u ^ REM) << 6));
      v = dppi<QC>(v);
    }
    return __int_as_float(v);
  }
}
template <unsigned LM> __device__ __forceinline__ v2f lane_xor2(v2f v) {
  if constexpr (LM == 0u) return v;
  v2f r;
  r.x = lane_xor1<LM>(v.x);
  r.y = lane_xor1<LM>(v.y);
  return r;
}

// ================= NEW KERNEL: transfer-chain expectation =================
// block = batch element, 64 threads (1 wave). lane = 4w + c, c=(cb, cp).
using cxf = cx<float>;
__global__ __launch_bounds__(64) void qchain(const float* __restrict__ x,
                                             const float* __restrict__ params,
                                             float* __restrict__ out) {
  __shared__ cxf Ssh[NW][2];      // layer-0+enc product-state columns
  __shared__ cxf Msh[NW][2][2];   // M_j = G1^dag Z G1 (batch-independent)

  const int bat = blockIdx.x;
  const int t = threadIdx.x;

  if (t < NW) {
    v2f m[4];
    make_mat(params[t * 3 + 0] + x[bat * NW + t], params[t * 3 + 1], params[t * 3 + 2], m);
    Ssh[t][0] = {m[0].x, m[0].y};
    Ssh[t][1] = {m[2].x, m[2].y};
  } else if (t < 2 * NW) {
    const int j = t - NW;
    v2f m[4];
    make_mat(params[NW * 3 + j * 3 + 0], params[NW * 3 + j * 3 + 1],
             params[NW * 3 + j * 3 + 2], m);
    const cxf g00{m[0].x, m[0].y}, g01{m[1].x, m[1].y};
    const cxf g10{m[2].x, m[2].y}, g11{m[3].x, m[3].y};
    Msh[j][0][0] = cj(g00) * g00 - cj(g10) * g10;
    Msh[j][0][1] = cj(g00) * g01 - cj(g10) * g11;
    Msh[j][1][0] = cj(g01) * g00 - cj(g11) * g10;
    Msh[j][1][1] = cj(g01) * g01 - cj(g11) * g11;
  }
  __syncthreads();

  const int w = t >> 2, c = t & 3;
  if (w < NW) {
    const unsigned Sm = qct.S[w];  // wire j in support iff bit (13-j)
    auto sg = [&](int j, int b) { return Ssh[j][b]; };
    auto mg = [&](int j, int r, int cc) {
      const bool inS = (Sm >> (13 - j)) & 1u;
      const cxf I = (r == cc) ? cxf{1.f, 0.f} : cxf{0.f, 0.f};
      const cxf F = Msh[j][r][cc];
      return inS ? F : I;
    };
    const cxf E = contract_case<NW, float>(sg, mg, c & 1, c >> 1);
    float r = E.re;
    r += lane_xor1<1>(r);
    r += lane_xor1<2>(r);
    if (c == 0) out[bat * NW + w] = r;
  }
}

// ================= FALLBACK KERNEL (R9, hardware-verified, unchanged) =============
template <unsigned RM>
__device__ __forceinline__ void gate_reg(v2f (&a)[16], const float4* G) {
  const float4 A0 = G[0], A1 = G[1], A2 = G[2], A3 = G[3];
  v2f m00, m01, m10, m11, s00, s01, s10, s11;
  m00.x = A0.x; m00.y = A0.y; m01.x = A0.z; m01.y = A0.w;
  m10.x = A1.x; m10.y = A1.y; m11.x = A1.z; m11.y = A1.w;
  s00.x = A2.x; s00.y = A2.y; s01.x = A2.z; s01.y = A2.w;
  s10.x = A3.x; s10.y = A3.y; s11.x = A3.z; s11.y = A3.w;
#pragma unroll
  for (int r = 0; r < 16; ++r) {
    if (r & (int)RM) continue;
    const int r1 = r | (int)RM;
    const v2f A = a[r], B = a[r1];
    a[r] = A.x * m00 + A.y * s00 + B.x * m01 + B.y * s01;
    a[r1] = A.x * m10 + A.y * s10 + B.x * m11 + B.y * s11;
  }
}
template <unsigned LM>
__device__ __forceinline__ void gate_dpp(v2f (&a)[16], const float4* G, bool role) {
  const float4 A0 = G[0], A1 = G[1], A2 = G[2], A3 = G[3];
  v2f m00, m01, m10, m11, s00, s01, s10, s11;
  m00.x = A0.x; m00.y = A0.y; m01.x = A0.z; m01.y = A0.w;
  m10.x = A1.x; m10.y = A1.y; m11.x = A1.z; m11.y = A1.w;
  s00.x = A2.x; s00.y = A2.y; s01.x = A2.z; s01.y = A2.w;
  s10.x = A3.x; s10.y = A3.y; s11.x = A3.z; s11.y = A3.w;
  const v2f f0 = role ? m11 : m00, f0s = role ? s11 : s00;
  const v2f f1 = role ? m10 : m01, f1s = role ? s10 : s01;
#pragma unroll
  for (int r = 0; r < 16; ++r) {
    const v2f P = lane_xor2<LM>(a[r]);
    const v2f A = a[r];
    a[r] = A.x * f0 + A.y * f0s + P.x * f1 + P.y * f1s;
  }
}

__global__ __launch_bounds__(NT, 4) void qsim(const float* __restrict__ x,
                                              const float* __restrict__ params,
                                              float* __restrict__ out) {
  __shared__ v2f stx[16384];
  __shared__ v2f v0[NW][2];
  __shared__ float4 gq[NW][4];
  __shared__ v2f Ahi[128];
  __shared__ v2f BloP[8][17];
  __shared__ float red[16][NW];

  const int bat = blockIdx.x;
  const int t = threadIdx.x;
  const unsigned ln = (unsigned)t & 63u, wv = (unsigned)t >> 6;

  if (t < 2 * NW) {
    const int layer = (t >= NW);
    const int w = t - layer * NW;
    v2f m[4];
    if (!layer) {
      make_mat(params[w * 3 + 0] + x[bat * NW + w], params[w * 3 + 1], params[w * 3 + 2], m);
      v0[w][0] = m[0];
      v0[w][1] = m[2];
    } else {
      make_mat(params[NW * 3 + w * 3 + 0], params[NW * 3 + w * 3 + 1],
               params[NW * 3 + w * 3 + 2], m);
      const v2f s0 = vswap(m[0]), s1 = vswap(m[1]), s2 = vswap(m[2]), s3 = vswap(m[3]);
      gq[w][0] = make_float4(m[0].x, m[0].y, m[1].x, m[1].y);
      gq[w][1] = make_float4(m[2].x, m[2].y, m[3].x, m[3].y);
      gq[w][2] = make_float4(s0.x, s0.y, s1.x, s1.y);
      gq[w][3] = make_float4(s2.x, s2.y, s3.x, s3.y);
    }
  }
  __syncthreads();
  if (t < 128) {
    v2f pa; pa.x = 1.f; pa.y = 0.f;
#pragma unroll
    for (int w = 0; w < 7; ++w) pa = cmulv(pa, v0[w][(t >> (6 - w)) & 1]);
    Ahi[t] = pa;
    v2f pb; pb.x = 1.f; pb.y = 0.f;
#pragma unroll
    for (int w = 7; w < 14; ++w) pb = cmulv(pb, v0[w][(t >> (13 - w)) & 1]);
    BloP[t >> 4][t & 15] = pb;
  }
  __syncthreads();

  const unsigned bb = (ln << 5) | ((wv & 7u) << 11) | (wv >> 3);
  const unsigned qb = ((bb ^ (bb >> 1)) ^ ((bb & 1u) * 0x3000u)) & 0x3FFFu;

  v2f a[16];
  {
    const v2f ahi = Ahi[qb >> 7];
    const v2f ahis = vswap(ahi);
    const unsigned q7 = qb & 127u;
#pragma unroll
    for (int r = 0; r < 16; ++r) {
      const unsigned j = q7 ^ (((unsigned)r << 1) ^ (unsigned)r);
      const v2f b = BloP[j >> 4][j & 15u];
      a[r] = b.x * ahi + b.y * ahis;
    }
  }

  gate_reg<1>(a, gq[12]);
  gate_reg<2>(a, gq[11]);
  gate_reg<4>(a, gq[10]);
  gate_reg<8>(a, gq[9]);
  gate_dpp<1>(a, gq[8], (ln & 1u) != 0);
  gate_dpp<2>(a, gq[7], (ln & 2u) != 0);
  gate_dpp<4>(a, gq[6], (ln & 4u) != 0);
  gate_dpp<8>(a, gq[5], (ln & 8u) != 0);

  {
    const unsigned bw = bb ^ ((ln & 0xFu) << 1);
#pragma unroll
    for (int r = 0; r < 16; ++r) stx[bw ^ ((unsigned)r << 1)] = a[r];
  }
  __syncthreads();
  const unsigned brb = (wv << 1) | (((ln >> 2) & 0xFu) << 5) | ((ln & 1u) << 9) |
                       (((ln >> 1) & 1u) << 10);
  {
    const unsigned br = brb ^ (((brb >> 5) & 0xFu) << 1);
#pragma unroll
    for (int r = 0; r < 16; ++r)
      a[r] = stx[br | (((unsigned)r & 7u) << 11) | ((unsigned)r >> 3)];
  }

  gate_dpp<1>(a, gq[4], (ln & 1u) != 0);
  gate_dpp<2>(a, gq[3], (ln & 2u) != 0);
  gate_reg<1>(a, gq[2]);
  gate_reg<2>(a, gq[1]);
  gate_reg<4>(a, gq[0]);
  gate_reg<8>(a, gq[13]);

  float T[16];
#pragma unroll
  for (int r = 0; r < 16; ++r) T[r] = fmaf(a[r].x, a[r].x, a[r].y * a[r].y);
#pragma unroll
  for (int s = 1; s < 16; s <<= 1) {
#pragma unroll
    for (int r = 0; r < 16; ++r) {
      if (!(r & s)) {
        float u = T[r], v = T[r ^ s];
        T[r] = u + v;
        T[r ^ s] = u - v;
      }
    }
  }

#pragma unroll
  for (int w = 0; w < NW; ++w) {
    constexpr unsigned Rr[NW] = {rbt.v[0], rbt.v[1], rbt.v[2], rbt.v[3], rbt.v[4],
                                 rbt.v[5], rbt.v[6], rbt.v[7], rbt.v[8], rbt.v[9],
                                 rbt.v[10], rbt.v[11], rbt.v[12], rbt.v[13]};
    const unsigned R = Rr[w];
    const unsigned m = ((R >> 11) & 1u) | (((R >> 12) & 1u) << 1) | (((R >> 13) & 1u) << 2) |
                       ((R & 1u) << 3);
    float val = T[m];
    val = (__popc(brb & R) & 1) ? -val : val;
    val += lane_xor1<1>(val);
    val += lane_xor1<2>(val);
    { float u = lane_xor1<4>(val); val += u; }
    val += lane_xor1<8>(val);
    val += __shfl_xor(val, 16, 64);
    val += __shfl_xor(val, 32, 64);
    if ((t & 63) == 0) red[wv][w] = val;
  }
  __syncthreads();
  if (t < NW) {
    float s = 0.f;
#pragma unroll
    for (int i = 0; i < 16; ++i) s += red[i][t];
    out[bat * NW + t] = s;
  }
}

extern "C" void kernel_launch(void* const* d_in, const int* in_sizes, int n_in,
                              void* d_out, int out_size, void* d_ws, size_t ws_size,
                              hipStream_t stream) {
  (void)in_sizes; (void)n_in; (void)d_ws; (void)ws_size; (void)out_size;
  const float* x = (const float*)d_in[0];
  const float* params = (const float*)d_in[1];
  float* out = (float*)d_out;
  if constexpr (CHAIN_OK) {
    qchain<<<dim3(BATCH), dim3(64), 0, stream>>>(x, params, out);
  } else {
    qsim<<<dim3(BATCH), dim3(NT), 0, stream>>>(x, params, out);
  }
}